// Round 1
// baseline (832.978 us; speedup 1.0000x reference)
//
#include <hip/hip_runtime.h>
#include <math.h>

// Attention_80779744903968 — round 4:
//   Port all MFMA GEMMs to a counted-vmcnt pipelined schedule (T3+T4+T5):
//   BM=256 x BN=128 x BK=64, 512 threads (8 waves, 64x64/wave), 3-slot LDS
//   rotation (144 KB), stage tile t+2 while computing tile t, vmcnt(6) per
//   K-tile (never 0 in steady state), raw s_barrier (no vmcnt drain),
//   s_setprio around the MFMA cluster. bf16x3 is expressed as 3 K-chunks
//   (Ah*Bh, Al*Bh, Ah*Bl) over the same 2-operand pipeline.
//
//   splits: q->q_hi/q_lo (bf16), W_in->hi/lo (bf16), W_out->fp16, enc->hi/lo
//   K1: z  = q·W_in^T        bf16 3-chunk, out z_hi/z_lo bf16
//   K2: P  = z·enc^T         bf16 3-chunk, batched, fp32 -> d_out
//   K3: softmax (==0 -> -inf quirk), fp32 -> Pb fp16
//   Q : q fp32 -> q_f16                      (into z_lo slot)
//   T : enc fp32 [S,B,H] -> eT fp16 [B][H][S] (into e_lo slot)
//   K4: C  = Pb·eT^T         fp16 1-chunk, out C_f16  (into z_hi slot)
//   K5: out= tanh([C,q]·W_out^T + b)  fp16 2-chunk, fp32 -> d_out

// ---------------------------------------------------------------- helpers
__device__ inline unsigned short f2bf(float x) {           // RNE float->bf16
    unsigned int u = __float_as_uint(x);
    u += 0x7fffu + ((u >> 16) & 1u);
    return (unsigned short)(u >> 16);
}
__device__ inline float bf2f(unsigned short h) {
    return __uint_as_float(((unsigned int)h) << 16);
}
__device__ inline unsigned short f2h(float x) {            // RNE float->fp16
    _Float16 h = (_Float16)x;
    return *(unsigned short*)&h;
}

typedef __attribute__((ext_vector_type(8))) short    short8; // 8 bf16
typedef __attribute__((ext_vector_type(8))) _Float16 half8;  // 8 fp16
typedef __attribute__((ext_vector_type(4))) float    f32x4;

__device__ inline void gld_lds16(const void* g, void* l) {
    __builtin_amdgcn_global_load_lds(
        (const __attribute__((address_space(1))) unsigned int*)g,
        (__attribute__((address_space(3))) unsigned int*)l, 16, 0, 0);
}

// barrier WITHOUT the __syncthreads() vmcnt(0) drain; memory-fenced for the
// compiler so LDS reads/writes can't migrate across it.
#define BAR() do { asm volatile("" ::: "memory"); \
                   __builtin_amdgcn_s_barrier();  \
                   asm volatile("" ::: "memory"); } while (0)
#define VM6() asm volatile("s_waitcnt vmcnt(6)" ::: "memory")
#define VM0() asm volatile("s_waitcnt vmcnt(0)" ::: "memory")

// LDS tile layout: [row][granule], granule g of row r stored at slot g^(r&7)
// (16B granules) -> frag reads are <=2-way conflicts (free, m136).
__device__ inline short8 frag_ld(const short* Ls, int rowbase, int ks8, int lane) {
    const int r = lane & 15, q = lane >> 4;
    return *(const short8*)&Ls[(rowbase + r) * 64 + (((ks8 + q) ^ (r & 7)) << 3)];
}

template<int DT>   // 0 = bf16, 1 = fp16
__device__ inline f32x4 mfma16(short8 a, short8 b, f32x4 c) {
    if constexpr (DT == 0)
        return __builtin_amdgcn_mfma_f32_16x16x32_bf16(a, b, c, 0, 0, 0);
    else
        return __builtin_amdgcn_mfma_f32_16x16x32_f16(
            __builtin_bit_cast(half8, a), __builtin_bit_cast(half8, b), c, 0, 0, 0);
}

// one staging issue: per wave, 8 rows x 64 cols (1 KB contiguous LDS dest);
// global source pre-swizzled so the linear LDS write lands swizzled (m173).
__device__ inline void stage1(const unsigned short* gk, long ld, short* slot,
                              int rowbase /*wave-uniform*/, int lane) {
    const int row = rowbase + (lane >> 3);
    const int g   = (lane & 7) ^ (row & 7);
    gld_lds16(gk + (long)row * ld + (g << 3), slot + rowbase * 64);
}

// ------------------------------------------------- pipelined chunked GEMM
// C = sum_c Ac·Bc^T, all chunks K=1024 (16 K-tiles of 64).
// OUT_MODE: 0 = fp16 out, 1 = bf16 hi/lo split out, 2 = fp32 out,
//           3 = tanh(acc+bias) fp32 out
template<int DT, int OUT_MODE>
__global__ __launch_bounds__(512, 2)
void gemm8p(const unsigned short* __restrict__ A0, const unsigned short* __restrict__ A1,
            const unsigned short* __restrict__ A2,
            const unsigned short* __restrict__ B0, const unsigned short* __restrict__ B1,
            const unsigned short* __restrict__ B2,
            float* __restrict__ Of, unsigned short* __restrict__ Oh,
            unsigned short* __restrict__ Ol, const float* __restrict__ bias,
            int NT, long lda, long ldb, long ldc, long sA, long sB, long sC)
{
    // 3-slot rotation: slot t%3 computed, slot (t+2)%3 staged, (t+1)%3 idle.
    __shared__ short LA[3 * 256 * 64];   // 96 KB
    __shared__ short LB[3 * 128 * 64];   // 48 KB

    const int tid  = threadIdx.x;
    const int wid  = tid >> 6, lane = tid & 63;
    const int wm   = (wid & 3) << 6;     // 0,64,128,192  (M sub-tile)
    const int wn   = (wid >> 2) << 6;    // 0,64          (N sub-tile)
    const int rb8  = wid << 3;           // wave's 8-row offset inside a 64-row issue
    const long m0 = (long)blockIdx.y * 256, n0 = (long)blockIdx.x * 128;
    const int bz = blockIdx.z;

    f32x4 acc[4][4];
#pragma unroll
    for (int i = 0; i < 4; ++i)
#pragma unroll
        for (int j = 0; j < 4; ++j) acc[i][j] = (f32x4){0.f, 0.f, 0.f, 0.f};

    // ---- prologue: stage K-tiles 0 and 1 (both in chunk 0)
    {
        const unsigned short* Ab = A0 + (long)bz * sA + m0 * lda;
        const unsigned short* Bb = B0 + (long)bz * sB + n0 * ldb;
#pragma unroll
        for (int pt = 0; pt < 2; ++pt) {
            const unsigned short* Ag = Ab + pt * 64;
            const unsigned short* Bg = Bb + pt * 64;
            short* As = LA + pt * 16384;
            short* Bs = LB + pt * 8192;
            stage1(Ag, lda, As, 0   + rb8, lane);
            stage1(Ag, lda, As, 64  + rb8, lane);
            stage1(Ag, lda, As, 128 + rb8, lane);
            stage1(Ag, lda, As, 192 + rb8, lane);
            stage1(Bg, ldb, Bs, 0   + rb8, lane);
            stage1(Bg, ldb, Bs, 64  + rb8, lane);
        }
        VM6();   // tile 0 landed (own wave), tile 1 in flight
        BAR();   // tile 0 visible to all waves
    }

    for (int t = 0; t < NT; ++t) {
        const int s = t % 3;
        const short* As = LA + s * 16384;
        const short* Bs = LB + s * 8192;

        const int t2 = t + 2;
        const bool st = t2 < NT;
        const unsigned short* A2g = nullptr;
        const unsigned short* B2g = nullptr;
        short* As2 = nullptr;
        short* Bs2 = nullptr;
        if (st) {
            const int c2 = t2 >> 4;                 // chunk (K=1024 -> 16 tiles)
            const long kk2 = (long)(t2 & 15) << 6;  // k-offset within chunk
            const unsigned short* Ac = (c2 == 0) ? A0 : ((c2 == 1) ? A1 : A2);
            const unsigned short* Bc = (c2 == 0) ? B0 : ((c2 == 1) ? B1 : B2);
            A2g = Ac + (long)bz * sA + m0 * lda + kk2;
            B2g = Bc + (long)bz * sB + n0 * ldb + kk2;
            const int s2 = t2 % 3;
            As2 = LA + s2 * 16384;
            Bs2 = LB + s2 * 8192;
        }

        // ---------------- phase 0 (k-slice 0)
        {
            short8 a[4], b[4];
#pragma unroll
            for (int i = 0; i < 4; ++i) a[i] = frag_ld(As, wm + i * 16, 0, lane);
#pragma unroll
            for (int j = 0; j < 4; ++j) b[j] = frag_ld(Bs, wn + j * 16, 0, lane);
            if (st) {
                stage1(A2g, lda, As2, 0   + rb8, lane);
                stage1(A2g, lda, As2, 64  + rb8, lane);
                stage1(A2g, lda, As2, 128 + rb8, lane);
            }
            BAR();
            __builtin_amdgcn_s_setprio(1);
#pragma unroll
            for (int i = 0; i < 4; ++i)
#pragma unroll
                for (int j = 0; j < 4; ++j)
                    acc[i][j] = mfma16<DT>(a[i], b[j], acc[i][j]);
            __builtin_amdgcn_s_setprio(0);
            BAR();
        }

        // ---------------- phase 1 (k-slice 1)
        {
            short8 a[4], b[4];
#pragma unroll
            for (int i = 0; i < 4; ++i) a[i] = frag_ld(As, wm + i * 16, 4, lane);
#pragma unroll
            for (int j = 0; j < 4; ++j) b[j] = frag_ld(Bs, wn + j * 16, 4, lane);
            if (st) {
                stage1(A2g, lda, As2, 192 + rb8, lane);
                stage1(B2g, ldb, Bs2, 0   + rb8, lane);
                stage1(B2g, ldb, Bs2, 64  + rb8, lane);
            }
            // counted wait: tile t+1's 6 loads (oldest) complete; tile t+2's
            // 6 stay in flight across the barrier. Tail (no stage) drains.
            if (st) VM6(); else VM0();
            BAR();
            __builtin_amdgcn_s_setprio(1);
#pragma unroll
            for (int i = 0; i < 4; ++i)
#pragma unroll
                for (int j = 0; j < 4; ++j)
                    acc[i][j] = mfma16<DT>(a[i], b[j], acc[i][j]);
            __builtin_amdgcn_s_setprio(0);
            BAR();
        }
    }

    // epilogue — C/D map: col = lane&15, row = (lane>>4)*4 + reg (m89)
    const int qq = lane >> 4, r = lane & 15;
#pragma unroll
    for (int i = 0; i < 4; ++i)
#pragma unroll
        for (int rr = 0; rr < 4; ++rr) {
            const long grow = m0 + wm + i * 16 + qq * 4 + rr;
#pragma unroll
            for (int j = 0; j < 4; ++j) {
                const long gcol = n0 + wn + j * 16 + r;
                const float v = acc[i][j][rr];
                const long off = (long)bz * sC + grow * ldc + gcol;
                if constexpr (OUT_MODE == 1) {
                    unsigned short h = f2bf(v);
                    Oh[off] = h;
                    Ol[off] = f2bf(v - bf2f(h));
                } else if constexpr (OUT_MODE == 2) {
                    Of[off] = v;
                } else if constexpr (OUT_MODE == 0) {
                    Oh[off] = f2h(v);
                } else {
                    Of[off] = tanhf(v + bias[gcol]);
                }
            }
        }
}

// ---------------------------------------------------------------- casts
template<bool HAS_LO>
__global__ __launch_bounds__(256)
void split_f32_bf16(const float* __restrict__ x, unsigned short* __restrict__ hi,
                    unsigned short* __restrict__ lo, int n4)
{
    const int i = blockIdx.x * 256 + threadIdx.x;
    if (i >= n4) return;
    const float4 v = ((const float4*)x)[i];
    ushort4 h;
    h.x = f2bf(v.x); h.y = f2bf(v.y); h.z = f2bf(v.z); h.w = f2bf(v.w);
    ((ushort4*)hi)[i] = h;
    if constexpr (HAS_LO) {
        ushort4 l;
        l.x = f2bf(v.x - bf2f(h.x)); l.y = f2bf(v.y - bf2f(h.y));
        l.z = f2bf(v.z - bf2f(h.z)); l.w = f2bf(v.w - bf2f(h.w));
        ((ushort4*)lo)[i] = l;
    }
}

__global__ __launch_bounds__(256)
void conv_f32_f16(const float* __restrict__ x, unsigned short* __restrict__ o, int n4)
{
    const int i = blockIdx.x * 256 + threadIdx.x;
    if (i >= n4) return;
    const float4 v = ((const float4*)x)[i];
    ushort4 h;
    h.x = f2h(v.x); h.y = f2h(v.y); h.z = f2h(v.z); h.w = f2h(v.w);
    ((ushort4*)o)[i] = h;
}

// enc fp32 [S,B,H] -> eT fp16 [B][H][S]; 64x64 tiles
__global__ __launch_bounds__(256)
void transpose_enc_f16(const float* __restrict__ E, unsigned short* __restrict__ ET)
{
    __shared__ unsigned short L[64][72];
    const int s0 = blockIdx.x * 64, h0 = blockIdx.y * 64, b = blockIdx.z;
    const int tid = threadIdx.x;
#pragma unroll
    for (int io = 0; io < 2; ++io) {
        const int g = io * 256 + tid;
        const int rs = g >> 3, c8 = (g & 7) * 8;
        const float* src = E + ((long)(s0 + rs) * 32 + b) * 1024 + h0 + c8;
        const float4 v0 = *(const float4*)(src);
        const float4 v1 = *(const float4*)(src + 4);
        L[rs][c8 + 0] = f2h(v0.x); L[rs][c8 + 1] = f2h(v0.y);
        L[rs][c8 + 2] = f2h(v0.z); L[rs][c8 + 3] = f2h(v0.w);
        L[rs][c8 + 4] = f2h(v1.x); L[rs][c8 + 5] = f2h(v1.y);
        L[rs][c8 + 6] = f2h(v1.z); L[rs][c8 + 7] = f2h(v1.w);
    }
    __syncthreads();
#pragma unroll
    for (int io = 0; io < 2; ++io) {
        const int g = io * 256 + tid;
        const int rh = g >> 3, c8 = (g & 7) * 8;
        unsigned short t[8];
#pragma unroll
        for (int j = 0; j < 8; ++j) t[j] = L[c8 + j][rh];
        unsigned short* dst = ET + ((long)b * 1024 + h0 + rh) * 1024 + s0 + c8;
        *(ushort4*)(dst)     = *(const ushort4*)&t[0];
        *(ushort4*)(dst + 4) = *(const ushort4*)&t[4];
    }
}

// -------------------------------------------------- softmax (fp16 out)
__global__ __launch_bounds__(256)
void softmax_p_f16(const float* __restrict__ P, unsigned short* __restrict__ Pb)
{
    const int row  = blockIdx.x * 4 + (threadIdx.x >> 6);
    const int lane = threadIdx.x & 63;
    const float* p = P + (long)row * 1024 + lane * 4;
    unsigned short* pb = Pb + (long)row * 1024 + lane * 4;

    float4 v[4];
    float mx = -INFINITY;
#pragma unroll
    for (int i = 0; i < 4; ++i) {
        v[i] = *(const float4*)(p + i * 256);
        v[i].x = (v[i].x == 0.f) ? -INFINITY : v[i].x;
        v[i].y = (v[i].y == 0.f) ? -INFINITY : v[i].y;
        v[i].z = (v[i].z == 0.f) ? -INFINITY : v[i].z;
        v[i].w = (v[i].w == 0.f) ? -INFINITY : v[i].w;
        mx = fmaxf(mx, fmaxf(fmaxf(v[i].x, v[i].y), fmaxf(v[i].z, v[i].w)));
    }
#pragma unroll
    for (int o = 32; o > 0; o >>= 1) mx = fmaxf(mx, __shfl_xor(mx, o, 64));

    float sum = 0.f;
#pragma unroll
    for (int i = 0; i < 4; ++i) {
        v[i].x = __expf(v[i].x - mx); v[i].y = __expf(v[i].y - mx);
        v[i].z = __expf(v[i].z - mx); v[i].w = __expf(v[i].w - mx);
        sum += v[i].x + v[i].y + v[i].z + v[i].w;
    }
#pragma unroll
    for (int o = 32; o > 0; o >>= 1) sum += __shfl_xor(sum, o, 64);

    const float inv = 1.f / sum;
#pragma unroll
    for (int i = 0; i < 4; ++i) {
        ushort4 u;
        u.x = f2h(v[i].x * inv); u.y = f2h(v[i].y * inv);
        u.z = f2h(v[i].z * inv); u.w = f2h(v[i].w * inv);
        *(ushort4*)(pb + i * 256) = u;
    }
}

// ================================================================ fallback
// (verified round-1 fp32 path, used only if ws_size < 264 MiB)
#define BM 128
#define BN 128
#define BKT 16

template<bool BT, bool DO_TANH, bool CAT_A>
__global__ __launch_bounds__(256)
void sgemm(const float* __restrict__ A, const float* __restrict__ A2,
           const float* __restrict__ Bmat, const float* __restrict__ bias,
           float* __restrict__ C,
           int M, int N, int K, int Ksplit,
           int lda, int ldb, int ldc,
           long sA, long sB, long sC)
{
    __shared__ float Asb[BKT][BM];
    __shared__ float Bsb[BKT][BN];

    const int bz = blockIdx.z;
    const float* Ab = A + (long)bz * sA;
    const float* Bb = Bmat + (long)bz * sB;
    float* Cb = C + (long)bz * sC;

    const int tid = threadIdx.x;
    const int m0 = blockIdx.y * BM;
    const int n0 = blockIdx.x * BN;
    const int tx = tid & 15;
    const int ty = tid >> 4;

    float acc[8][8];
#pragma unroll
    for (int i = 0; i < 8; ++i)
#pragma unroll
        for (int j = 0; j < 8; ++j) acc[i][j] = 0.f;

    for (int kk = 0; kk < K; kk += BKT) {
        const float* Asrc = Ab;
        int acol = kk;
        if constexpr (CAT_A) {
            if (kk >= Ksplit) { Asrc = A2; acol = kk - Ksplit; }
        }
#pragma unroll
        for (int i = 0; i < 2; ++i) {
            int f = i * 256 + tid;
            int row = f >> 2;
            int k4 = (f & 3) << 2;
            float4 v = *(const float4*)(Asrc + (long)(m0 + row) * lda + acol + k4);
            Asb[k4 + 0][row] = v.x; Asb[k4 + 1][row] = v.y;
            Asb[k4 + 2][row] = v.z; Asb[k4 + 3][row] = v.w;
        }
        if constexpr (BT) {
#pragma unroll
            for (int i = 0; i < 2; ++i) {
                int f = i * 256 + tid;
                int row = f >> 2;
                int k4 = (f & 3) << 2;
                float4 v = *(const float4*)(Bb + (long)(n0 + row) * ldb + kk + k4);
                Bsb[k4 + 0][row] = v.x; Bsb[k4 + 1][row] = v.y;
                Bsb[k4 + 2][row] = v.z; Bsb[k4 + 3][row] = v.w;
            }
        } else {
#pragma unroll
            for (int i = 0; i < 2; ++i) {
                int f = i * 256 + tid;
                int kr = f >> 5;
                int n4 = (f & 31) << 2;
                float4 v = *(const float4*)(Bb + (long)(kk + kr) * ldb + n0 + n4);
                *(float4*)&Bsb[kr][n4] = v;
            }
        }
        __syncthreads();
#pragma unroll
        for (int k = 0; k < BKT; ++k) {
            float a[8], bv[8];
            *(float4*)&a[0]  = *(const float4*)&Asb[k][ty * 4];
            *(float4*)&a[4]  = *(const float4*)&Asb[k][ty * 4 + 64];
            *(float4*)&bv[0] = *(const float4*)&Bsb[k][tx * 4];
            *(float4*)&bv[4] = *(const float4*)&Bsb[k][tx * 4 + 64];
#pragma unroll
            for (int i = 0; i < 8; ++i)
#pragma unroll
                for (int j = 0; j < 8; ++j)
                    acc[i][j] = fmaf(a[i], bv[j], acc[i][j]);
        }
        __syncthreads();
    }
#pragma unroll
    for (int i = 0; i < 8; ++i) {
        int rrow = m0 + ty * 4 + (i & 3) + ((i >> 2) << 6);
        float* crow = Cb + (long)rrow * ldc;
#pragma unroll
        for (int jj = 0; jj < 2; ++jj) {
            int c0 = n0 + tx * 4 + jj * 64;
            float4 v;
            v.x = acc[i][jj * 4 + 0]; v.y = acc[i][jj * 4 + 1];
            v.z = acc[i][jj * 4 + 2]; v.w = acc[i][jj * 4 + 3];
            if constexpr (DO_TANH) {
                v.x = tanhf(v.x + bias[c0 + 0]); v.y = tanhf(v.y + bias[c0 + 1]);
                v.z = tanhf(v.z + bias[c0 + 2]); v.w = tanhf(v.w + bias[c0 + 3]);
            }
            *(float4*)(crow + c0) = v;
        }
    }
}

__global__ __launch_bounds__(256)
void softmax_rows(float* __restrict__ P)
{
    const int row = blockIdx.x * 4 + (threadIdx.x >> 6);
    const int lane = threadIdx.x & 63;
    float* p = P + (long)row * 1024 + lane * 4;
    float4 v[4];
    float mx = -INFINITY;
#pragma unroll
    for (int i = 0; i < 4; ++i) {
        v[i] = *(const float4*)(p + i * 256);
        v[i].x = (v[i].x == 0.f) ? -INFINITY : v[i].x;
        v[i].y = (v[i].y == 0.f) ? -INFINITY : v[i].y;
        v[i].z = (v[i].z == 0.f) ? -INFINITY : v[i].z;
        v[i].w = (v[i].w == 0.f) ? -INFINITY : v[i].w;
        mx = fmaxf(mx, fmaxf(fmaxf(v[i].x, v[i].y), fmaxf(v[i].z, v[i].w)));
    }
#pragma unroll
    for (int o = 32; o > 0; o >>= 1) mx = fmaxf(mx, __shfl_xor(mx, o, 64));
    float sum = 0.f;
#pragma unroll
    for (int i = 0; i < 4; ++i) {
        v[i].x = __expf(v[i].x - mx); v[i].y = __expf(v[i].y - mx);
        v[i].z = __expf(v[i].z - mx); v[i].w = __expf(v[i].w - mx);
        sum += v[i].x + v[i].y + v[i].z + v[i].w;
    }
#pragma unroll
    for (int o = 32; o > 0; o >>= 1) sum += __shfl_xor(sum, o, 64);
    const float inv = 1.f / sum;
#pragma unroll
    for (int i = 0; i < 4; ++i) {
        v[i].x *= inv; v[i].y *= inv; v[i].z *= inv; v[i].w *= inv;
        *(float4*)(p + i * 256) = v[i];
    }
}

// ================================================================ launch
extern "C" void kernel_launch(void* const* d_in, const int* in_sizes, int n_in,
                              void* d_out, int out_size, void* d_ws, size_t ws_size,
                              hipStream_t stream)
{
    (void)in_sizes; (void)n_in; (void)out_size;
    const int Bv = 32, T = 512, S = 1024, H = 1024;

    const float* q     = (const float*)d_in[0];
    const float* enc   = (const float*)d_in[1];
    const float* W_in  = (const float*)d_in[3];
    const float* W_out = (const float*)d_in[4];
    const float* b_out = (const float*)d_in[5];
    float* out = (float*)d_out;

    const size_t need = 264ull << 20;
    if (ws_size >= need) {
        char* w = (char*)d_ws;
        unsigned short* q_hi  = (unsigned short*)(w);                  // K1
        unsigned short* q_lo  = (unsigned short*)(w + (32ull << 20));  // K1; then Pb fp16
        unsigned short* z_hi  = (unsigned short*)(w + (64ull << 20));  // K1->K2; then C_f16
        unsigned short* z_lo  = (unsigned short*)(w + (96ull << 20));  // K1->K2; then q_f16
        unsigned short* e_hi  = (unsigned short*)(w + (128ull << 20)); // K2
        unsigned short* e_lo  = (unsigned short*)(w + (192ull << 20)); // K2; then eT fp16
        unsigned short* Wi_hi = (unsigned short*)(w + (256ull << 20));
        unsigned short* Wi_lo = (unsigned short*)(w + (258ull << 20));
        unsigned short* Wo16  = (unsigned short*)(w + (260ull << 20));

        unsigned short* Pb    = q_lo;   // fp16, after softmax
        unsigned short* q16   = z_lo;   // fp16, after K2
        unsigned short* eT    = e_lo;   // fp16, after K2
        unsigned short* C16   = z_hi;   // fp16, after K2

        split_f32_bf16<true ><<<16384, 256, 0, stream>>>(q, q_hi, q_lo, 4194304);
        split_f32_bf16<true ><<<1024,  256, 0, stream>>>(W_in, Wi_hi, Wi_lo, 262144);
        conv_f32_f16<<<2048, 256, 0, stream>>>(W_out, Wo16, 524288);
        split_f32_bf16<true ><<<32768, 256, 0, stream>>>(enc, e_hi, e_lo, 8388608);

        // K1: z = q·W_in^T  bf16, chunks (qh,Wh),(ql,Wh),(qh,Wl); out z_hi/z_lo
        gemm8p<0, 1><<<dim3(8, 64, 1), 512, 0, stream>>>(
            q_hi, q_lo, q_hi, Wi_hi, Wi_hi, Wi_lo,
            nullptr, z_hi, z_lo, nullptr,
            48, 1024, 1024, 1024, 0, 0, 0);

        // K2: P_b = z_b·enc_b^T  bf16, chunks (zh,eh),(zl,eh),(zh,el); fp32 -> d_out
        gemm8p<0, 2><<<dim3(8, 2, 32), 512, 0, stream>>>(
            z_hi, z_lo, z_hi, e_hi, e_hi, e_lo,
            (float*)d_out, nullptr, nullptr, nullptr,
            48, 1024, (long)Bv * H, 1024, (long)T * H, (long)H, (long)T * S);

        // K3: masked softmax, fp32 -> fp16 Pb
        softmax_p_f16<<<(Bv * T) / 4, 256, 0, stream>>>((const float*)d_out, Pb);

        // q fp32 -> fp16 (into z_lo, free after K2)
        conv_f32_f16<<<16384, 256, 0, stream>>>(q, q16, 4194304);

        // enc fp32 [S,B,H] -> eT fp16 [B][H][S] (into e_lo, free after K2)
        transpose_enc_f16<<<dim3(16, 16, 32), 256, 0, stream>>>(enc, eT);

        // K4: C_b = Pb_b · eT_b^T  (fp16, 1 chunk), out C_f16
        gemm8p<1, 0><<<dim3(8, 2, 32), 512, 0, stream>>>(
            Pb, nullptr, nullptr, eT, nullptr, nullptr,
            nullptr, C16, nullptr, nullptr,
            16, 1024, 1024, 1024, (long)T * S, (long)H * S, (long)T * H);

        // K5: out = tanh([C,q]·W_out^T + b)  (fp16, 2 chunks of K=1024)
        gemm8p<1, 3><<<dim3(8, 64, 1), 512, 0, stream>>>(
            C16, q16, nullptr, Wo16, Wo16 + 1024, nullptr,
            (float*)d_out, nullptr, nullptr, b_out,
            32, 1024, 2048, 1024, 0, 0, 0);
    } else {
        // -------- fallback: round-1 fp32 path --------
        float* Z = (float*)d_ws;
        float* P = Z + (size_t)Bv * T * H;
        dim3 blk(256);
        sgemm<true, false, false><<<dim3(H / BN, (Bv * T) / BM, 1), blk, 0, stream>>>(
            q, nullptr, W_in, nullptr, Z,
            Bv * T, H, H, 0, H, H, H, 0, 0, 0);
        sgemm<true, false, false><<<dim3(S / BN, T / BM, Bv), blk, 0, stream>>>(
            Z, nullptr, enc, nullptr, P,
            T, S, H, 0, H, Bv * H, S, (long)T * H, H, (long)T * S);
        softmax_rows<<<(Bv * T) / 4, blk, 0, stream>>>(P);
        sgemm<false, false, false><<<dim3(H / BN, T / BM, Bv), blk, 0, stream>>>(
            P, nullptr, enc, nullptr, Z,
            T, H, S, 0, S, Bv * H, H, (long)T * S, H, (long)T * H);
        sgemm<true, true, true><<<dim3(H / BN, (Bv * T) / BM, 1), blk, 0, stream>>>(
            Z, q, W_out, b_out, out,
            Bv * T, H, 2 * H, H, H, 2 * H, H, 0, 0, 0);
    }
}

// Round 2
// 666.472 us; speedup vs baseline: 1.2498x; 1.2498x over previous
//
#include <hip/hip_runtime.h>
#include <math.h>

// Attention_80779744903968 — round 5:
//   REVERT GEMMs to round-3 (chunk-fused bf16x3 / fp16, 128x128, 4 waves,
//   2 blocks/CU — proven 727 µs; round-4's 3-chunk pipeline was +50% HBM
//   traffic and regressed). New in this round:
//     * T1 XCD-aware block swizzle on K1/K5 (weights become L2-resident
//       per XCD; A-panels shared across the XCD's 8 N-blocks)
//     * fused prep passes: q-split also emits q16; enc-split also emits the
//       fp16 transpose eT (reads q and enc ONCE each, saving 192 MB of HBM
//       reads) — gated on ws_size >= 360 MiB, else exact round-3 sequence
//     * W_in split + W_out conv fused into one launch
//
//   splits: q->q_hi/q_lo (bf16) [+q16 fp16], W_in->hi/lo (bf16), W_out->fp16,
//           enc->hi/lo (bf16) [+eT fp16 transposed]
//   K1: z  = q·W_in^T        bf16x3 fused, out z_hi/z_lo bf16   [XCD swizzle]
//   K2: P  = z·enc^T         bf16x3 fused, batched, fp32 -> d_out
//   K3: softmax (==0 -> -inf quirk), fp32 -> Pb fp16
//   K4: C  = Pb·eT^T         fp16, out C_f16
//   K5: out= tanh([C,q]·W_out^T + b)  fp16 2-chunk, fp32 -> d_out [XCD swizzle]

// ---------------------------------------------------------------- helpers
__device__ inline unsigned short f2bf(float x) {           // RNE float->bf16
    unsigned int u = __float_as_uint(x);
    u += 0x7fffu + ((u >> 16) & 1u);
    return (unsigned short)(u >> 16);
}
__device__ inline float bf2f(unsigned short h) {
    return __uint_as_float(((unsigned int)h) << 16);
}
__device__ inline unsigned short f2h(float x) {            // RNE float->fp16
    _Float16 h = (_Float16)x;
    return *(unsigned short*)&h;
}

typedef __attribute__((ext_vector_type(8))) short    short8; // 8 bf16
typedef __attribute__((ext_vector_type(8))) _Float16 half8;  // 8 fp16
typedef __attribute__((ext_vector_type(4))) float    f32x4;

__device__ inline void gld_lds16(const void* g, void* l) {
    __builtin_amdgcn_global_load_lds(
        (const __attribute__((address_space(1))) unsigned int*)g,
        (__attribute__((address_space(3))) unsigned int*)l, 16, 0, 0);
}

// LDS tile layout: [row][granule], granule g of row r stored at slot g^(r&7)
// (16B granules) -> frag reads are <=2-way conflicts (free, m136).
__device__ inline short8 frag_ld(const short* Ls, int rowbase, int ks8, int lane) {
    const int r = lane & 15, q = lane >> 4;
    return *(const short8*)&Ls[(rowbase + r) * 64 + (((ks8 + q) ^ (r & 7)) << 3)];
}
__device__ inline half8 frag_ld_h(const short* Ls, int rowbase, int ks8, int lane) {
    const int r = lane & 15, q = lane >> 4;
    return *(const half8*)&Ls[(rowbase + r) * 64 + (((ks8 + q) ^ (r & 7)) << 3)];
}

// stage one 128x64-short tile; each wave covers rows rw..rw+31
__device__ inline void stage_tile(const unsigned short* g, long ld, short* lds,
                                  int rw, int lr, int gran) {
#pragma unroll
    for (int seg = 0; seg < 4; ++seg) {
        const int row = rw + seg * 8 + lr;
        gld_lds16(g + (long)row * ld + (gran << 3), lds + (rw + seg * 8) * 64);
    }
}

// XCD-aware bijective block swizzle for z==1 grids with (gx*gy)%8==0:
// consecutive remapped blocks land on one XCD -> weight panels L2-resident.
__device__ inline void xcd_swz(int& bx, int& by) {
    const int gx = gridDim.x;
    const int nwg = gx * gridDim.y;
    const int lin = by * gx + bx;
    const int cpx = nwg >> 3;
    const int swz = (lin & 7) * cpx + (lin >> 3);
    bx = swz % gx;
    by = swz / gx;
}

// ------------------------------------------------- chunk-fused bf16x3 GEMM
// C = Ah·Bh^T + Ah·Bl^T + Al·Bh^T  (all K-contiguous rows, NT)
// 128x128 tile, 4 waves x (4x4 of 16x16x32 bf16), BK=64, 64 KB LDS.
// OUT_MODE: 1 = hi/lo bf16 split out, 2 = fp32 out
template<int OUT_MODE, bool SWZ>
__global__ __launch_bounds__(256, 2)
void gemm_x3(const unsigned short* __restrict__ Ahg, const unsigned short* __restrict__ Alg,
             const unsigned short* __restrict__ Bhg, const unsigned short* __restrict__ Blg,
             float* __restrict__ Of, unsigned short* __restrict__ Oh,
             unsigned short* __restrict__ Ol,
             int K, long lda, long ldb, long ldc, long sA, long sB, long sC)
{
    __shared__ short Ah[128 * 64], Al[128 * 64], Bh[128 * 64], Bl[128 * 64];

    const int tid  = threadIdx.x;
    const int wave = tid >> 6, lane = tid & 63;
    const int wm = (wave & 1) << 6, wn = (wave >> 1) << 6;
    int bxi = blockIdx.x, byi = blockIdx.y;
    if constexpr (SWZ) xcd_swz(bxi, byi);
    const long m0 = (long)byi * 128, n0 = (long)bxi * 128;
    const int bz = blockIdx.z;

    const unsigned short* Ah0 = Ahg + (long)bz * sA + m0 * lda;
    const unsigned short* Al0 = Alg + (long)bz * sA + m0 * lda;
    const unsigned short* Bh0 = Bhg + (long)bz * sB + n0 * ldb;
    const unsigned short* Bl0 = Blg + (long)bz * sB + n0 * ldb;

    f32x4 acc[4][4];
#pragma unroll
    for (int i = 0; i < 4; ++i)
#pragma unroll
        for (int j = 0; j < 4; ++j) acc[i][j] = (f32x4){0.f, 0.f, 0.f, 0.f};

    const int lr   = lane >> 3;
    const int gran = (lane & 7) ^ lr;
    const int rw   = wave * 32;

    for (int k0 = 0; k0 < K; k0 += 64) {
        __syncthreads();
        stage_tile(Ah0 + k0, lda, Ah, rw, lr, gran);
        stage_tile(Al0 + k0, lda, Al, rw, lr, gran);
        stage_tile(Bh0 + k0, ldb, Bh, rw, lr, gran);
        stage_tile(Bl0 + k0, ldb, Bl, rw, lr, gran);
        __syncthreads();
#pragma unroll
        for (int ks = 0; ks < 2; ++ks) {
            short8 ah[4], al[4], bh[4], bl[4];
#pragma unroll
            for (int i = 0; i < 4; ++i) ah[i] = frag_ld(Ah, wm + i * 16, ks * 4, lane);
#pragma unroll
            for (int j = 0; j < 4; ++j) bh[j] = frag_ld(Bh, wn + j * 16, ks * 4, lane);
#pragma unroll
            for (int i = 0; i < 4; ++i)
#pragma unroll
                for (int j = 0; j < 4; ++j)
                    acc[i][j] = __builtin_amdgcn_mfma_f32_16x16x32_bf16(ah[i], bh[j], acc[i][j], 0, 0, 0);
#pragma unroll
            for (int j = 0; j < 4; ++j) bl[j] = frag_ld(Bl, wn + j * 16, ks * 4, lane);
#pragma unroll
            for (int i = 0; i < 4; ++i)
#pragma unroll
                for (int j = 0; j < 4; ++j)
                    acc[i][j] = __builtin_amdgcn_mfma_f32_16x16x32_bf16(ah[i], bl[j], acc[i][j], 0, 0, 0);
#pragma unroll
            for (int i = 0; i < 4; ++i) al[i] = frag_ld(Al, wm + i * 16, ks * 4, lane);
#pragma unroll
            for (int i = 0; i < 4; ++i)
#pragma unroll
                for (int j = 0; j < 4; ++j)
                    acc[i][j] = __builtin_amdgcn_mfma_f32_16x16x32_bf16(al[i], bh[j], acc[i][j], 0, 0, 0);
        }
    }

    // epilogue — C/D map: col = lane&15, row = (lane>>4)*4 + reg (m89)
    const int q = lane >> 4, r = lane & 15;
#pragma unroll
    for (int i = 0; i < 4; ++i)
#pragma unroll
        for (int rr = 0; rr < 4; ++rr) {
            const long grow = m0 + wm + i * 16 + q * 4 + rr;
#pragma unroll
            for (int j = 0; j < 4; ++j) {
                const long gcol = n0 + wn + j * 16 + r;
                const float v = acc[i][j][rr];
                const long off = (long)bz * sC + grow * ldc + gcol;
                if constexpr (OUT_MODE == 1) {
                    unsigned short h = f2bf(v);
                    Oh[off] = h;
                    Ol[off] = f2bf(v - bf2f(h));
                } else {
                    Of[off] = v;
                }
            }
        }
}

// ------------------------------------------------- fp16 GEMM (K4 / K5)
// C = sum_c Ac·Bc^T ; OUT_MODE: 0 = fp16 out, 3 = tanh(acc+bias) fp32 out
template<int NCHUNK, int OUT_MODE, bool SWZ>
__global__ __launch_bounds__(256, 2)
void gemm_f16(const unsigned short* __restrict__ A0, const unsigned short* __restrict__ A1,
              const unsigned short* __restrict__ B0, const unsigned short* __restrict__ B1,
              float* __restrict__ Of, unsigned short* __restrict__ Oh,
              const float* __restrict__ bias,
              int chunkK, long lda, long ldb, long ldc, long sA, long sB, long sC)
{
    __shared__ short As[128 * 64];
    __shared__ short Bs[128 * 64];

    const int tid  = threadIdx.x;
    const int wave = tid >> 6, lane = tid & 63;
    const int wm = (wave & 1) << 6, wn = (wave >> 1) << 6;
    int bxi = blockIdx.x, byi = blockIdx.y;
    if constexpr (SWZ) xcd_swz(bxi, byi);
    const long m0 = (long)byi * 128, n0 = (long)bxi * 128;
    const int bz = blockIdx.z;

    const unsigned short* Ap[2] = {A0, A1};
    const unsigned short* Bp[2] = {B0, B1};

    f32x4 acc[4][4];
#pragma unroll
    for (int i = 0; i < 4; ++i)
#pragma unroll
        for (int j = 0; j < 4; ++j) acc[i][j] = (f32x4){0.f, 0.f, 0.f, 0.f};

    const int lr   = lane >> 3;
    const int gran = (lane & 7) ^ lr;
    const int rw   = wave * 32;

#pragma unroll
    for (int c = 0; c < NCHUNK; ++c) {
        const unsigned short* Ac = Ap[c] + (long)bz * sA + m0 * lda;
        const unsigned short* Bc = Bp[c] + (long)bz * sB + n0 * ldb;
        for (int k0 = 0; k0 < chunkK; k0 += 64) {
            __syncthreads();
            stage_tile(Ac + k0, lda, As, rw, lr, gran);
            stage_tile(Bc + k0, ldb, Bs, rw, lr, gran);
            __syncthreads();
#pragma unroll
            for (int ks = 0; ks < 2; ++ks) {
                half8 af[4], bfv[4];
#pragma unroll
                for (int i = 0; i < 4; ++i) af[i]  = frag_ld_h(As, wm + i * 16, ks * 4, lane);
#pragma unroll
                for (int j = 0; j < 4; ++j) bfv[j] = frag_ld_h(Bs, wn + j * 16, ks * 4, lane);
#pragma unroll
                for (int i = 0; i < 4; ++i)
#pragma unroll
                    for (int j = 0; j < 4; ++j)
                        acc[i][j] = __builtin_amdgcn_mfma_f32_16x16x32_f16(af[i], bfv[j], acc[i][j], 0, 0, 0);
            }
        }
    }

    const int q = lane >> 4, r = lane & 15;
#pragma unroll
    for (int i = 0; i < 4; ++i)
#pragma unroll
        for (int rr = 0; rr < 4; ++rr) {
            const long grow = m0 + wm + i * 16 + q * 4 + rr;
#pragma unroll
            for (int j = 0; j < 4; ++j) {
                const long gcol = n0 + wn + j * 16 + r;
                const float v = acc[i][j][rr];
                const long off = (long)bz * sC + grow * ldc + gcol;
                if constexpr (OUT_MODE == 0) {
                    Oh[off] = f2h(v);
                } else {
                    Of[off] = tanhf(v + bias[gcol]);
                }
            }
        }
}

// ---------------------------------------------------------------- casts
// q split: hi/lo bf16 and (optionally) fp16 copy in the same read pass.
template<bool Q16>
__global__ __launch_bounds__(256)
void split_q_k(const float* __restrict__ x, unsigned short* __restrict__ hi,
               unsigned short* __restrict__ lo, unsigned short* __restrict__ h16,
               int n4)
{
    const int i = blockIdx.x * 256 + threadIdx.x;
    if (i >= n4) return;
    const float4 v = ((const float4*)x)[i];
    ushort4 h, l;
    h.x = f2bf(v.x); h.y = f2bf(v.y); h.z = f2bf(v.z); h.w = f2bf(v.w);
    l.x = f2bf(v.x - bf2f(h.x)); l.y = f2bf(v.y - bf2f(h.y));
    l.z = f2bf(v.z - bf2f(h.z)); l.w = f2bf(v.w - bf2f(h.w));
    ((ushort4*)hi)[i] = h;
    ((ushort4*)lo)[i] = l;
    if constexpr (Q16) {
        ushort4 f;
        f.x = f2h(v.x); f.y = f2h(v.y); f.z = f2h(v.z); f.w = f2h(v.w);
        ((ushort4*)h16)[i] = f;
    }
}

// plain hi/lo split (small-ws enc path)
__global__ __launch_bounds__(256)
void split_f32_bf16(const float* __restrict__ x, unsigned short* __restrict__ hi,
                    unsigned short* __restrict__ lo, int n4)
{
    const int i = blockIdx.x * 256 + threadIdx.x;
    if (i >= n4) return;
    const float4 v = ((const float4*)x)[i];
    ushort4 h, l;
    h.x = f2bf(v.x); h.y = f2bf(v.y); h.z = f2bf(v.z); h.w = f2bf(v.w);
    l.x = f2bf(v.x - bf2f(h.x)); l.y = f2bf(v.y - bf2f(h.y));
    l.z = f2bf(v.z - bf2f(h.z)); l.w = f2bf(v.w - bf2f(h.w));
    ((ushort4*)hi)[i] = h;
    ((ushort4*)lo)[i] = l;
}

__global__ __launch_bounds__(256)
void conv_f32_f16(const float* __restrict__ x, unsigned short* __restrict__ o, int n4)
{
    const int i = blockIdx.x * 256 + threadIdx.x;
    if (i >= n4) return;
    const float4 v = ((const float4*)x)[i];
    ushort4 h;
    h.x = f2h(v.x); h.y = f2h(v.y); h.z = f2h(v.z); h.w = f2h(v.w);
    ((ushort4*)o)[i] = h;
}

// W_in split + W_out conv fused (one launch; 262144 + 524288 float4s)
__global__ __launch_bounds__(256)
void prep_w_k(const float* __restrict__ Wi, unsigned short* __restrict__ Wih,
              unsigned short* __restrict__ Wil,
              const float* __restrict__ Wo, unsigned short* __restrict__ Wo16)
{
    const int i = blockIdx.x * 256 + threadIdx.x;
    if (i < 262144) {
        const float4 v = ((const float4*)Wi)[i];
        ushort4 h, l;
        h.x = f2bf(v.x); h.y = f2bf(v.y); h.z = f2bf(v.z); h.w = f2bf(v.w);
        l.x = f2bf(v.x - bf2f(h.x)); l.y = f2bf(v.y - bf2f(h.y));
        l.z = f2bf(v.z - bf2f(h.z)); l.w = f2bf(v.w - bf2f(h.w));
        ((ushort4*)Wih)[i] = h;
        ((ushort4*)Wil)[i] = l;
    } else {
        const int j = i - 262144;
        if (j < 524288) {
            const float4 v = ((const float4*)Wo)[j];
            ushort4 h;
            h.x = f2h(v.x); h.y = f2h(v.y); h.z = f2h(v.z); h.w = f2h(v.w);
            ((ushort4*)Wo16)[j] = h;
        }
    }
}

// enc fp32 [S,B,H] -> e_hi/e_lo bf16 [S,B,H] AND eT fp16 [B][H][S], one read.
__global__ __launch_bounds__(256)
void split_enc_t(const float* __restrict__ E, unsigned short* __restrict__ Eh,
                 unsigned short* __restrict__ El, unsigned short* __restrict__ ET)
{
    __shared__ unsigned short L[64][72];
    const int s0 = blockIdx.x * 64, h0 = blockIdx.y * 64, b = blockIdx.z;
    const int tid = threadIdx.x;
#pragma unroll
    for (int io = 0; io < 2; ++io) {
        const int g = io * 256 + tid;
        const int rs = g >> 3, c8 = (g & 7) * 8;
        const long base = ((long)(s0 + rs) * 32 + b) * 1024 + h0 + c8;
        const float4 v0 = *(const float4*)(E + base);
        const float4 v1 = *(const float4*)(E + base + 4);
        const float vv[8] = {v0.x, v0.y, v0.z, v0.w, v1.x, v1.y, v1.z, v1.w};
        unsigned short hi[8], lo[8];
#pragma unroll
        for (int j = 0; j < 8; ++j) {
            hi[j] = f2bf(vv[j]);
            lo[j] = f2bf(vv[j] - bf2f(hi[j]));
            L[rs][c8 + j] = f2h(vv[j]);
        }
        *(ushort4*)(Eh + base)     = *(const ushort4*)&hi[0];
        *(ushort4*)(Eh + base + 4) = *(const ushort4*)&hi[4];
        *(ushort4*)(El + base)     = *(const ushort4*)&lo[0];
        *(ushort4*)(El + base + 4) = *(const ushort4*)&lo[4];
    }
    __syncthreads();
#pragma unroll
    for (int io = 0; io < 2; ++io) {
        const int g = io * 256 + tid;
        const int rh = g >> 3, c8 = (g & 7) * 8;
        unsigned short t[8];
#pragma unroll
        for (int j = 0; j < 8; ++j) t[j] = L[c8 + j][rh];
        unsigned short* dst = ET + ((long)b * 1024 + h0 + rh) * 1024 + s0 + c8;
        *(ushort4*)(dst)     = *(const ushort4*)&t[0];
        *(ushort4*)(dst + 4) = *(const ushort4*)&t[4];
    }
}

// enc fp32 [S,B,H] -> eT fp16 [B][H][S]; 64x64 tiles (small-ws path)
__global__ __launch_bounds__(256)
void transpose_enc_f16(const float* __restrict__ E, unsigned short* __restrict__ ET)
{
    __shared__ unsigned short L[64][72];
    const int s0 = blockIdx.x * 64, h0 = blockIdx.y * 64, b = blockIdx.z;
    const int tid = threadIdx.x;
#pragma unroll
    for (int io = 0; io < 2; ++io) {
        const int g = io * 256 + tid;
        const int rs = g >> 3, c8 = (g & 7) * 8;
        const float* src = E + ((long)(s0 + rs) * 32 + b) * 1024 + h0 + c8;
        const float4 v0 = *(const float4*)(src);
        const float4 v1 = *(const float4*)(src + 4);
        L[rs][c8 + 0] = f2h(v0.x); L[rs][c8 + 1] = f2h(v0.y);
        L[rs][c8 + 2] = f2h(v0.z); L[rs][c8 + 3] = f2h(v0.w);
        L[rs][c8 + 4] = f2h(v1.x); L[rs][c8 + 5] = f2h(v1.y);
        L[rs][c8 + 6] = f2h(v1.z); L[rs][c8 + 7] = f2h(v1.w);
    }
    __syncthreads();
#pragma unroll
    for (int io = 0; io < 2; ++io) {
        const int g = io * 256 + tid;
        const int rh = g >> 3, c8 = (g & 7) * 8;
        unsigned short t[8];
#pragma unroll
        for (int j = 0; j < 8; ++j) t[j] = L[c8 + j][rh];
        unsigned short* dst = ET + ((long)b * 1024 + h0 + rh) * 1024 + s0 + c8;
        *(ushort4*)(dst)     = *(const ushort4*)&t[0];
        *(ushort4*)(dst + 4) = *(const ushort4*)&t[4];
    }
}

// -------------------------------------------------- softmax (fp16 out)
__global__ __launch_bounds__(256)
void softmax_p_f16(const float* __restrict__ P, unsigned short* __restrict__ Pb)
{
    const int row  = blockIdx.x * 4 + (threadIdx.x >> 6);
    const int lane = threadIdx.x & 63;
    const float* p = P + (long)row * 1024 + lane * 4;
    unsigned short* pb = Pb + (long)row * 1024 + lane * 4;

    float4 v[4];
    float mx = -INFINITY;
#pragma unroll
    for (int i = 0; i < 4; ++i) {
        v[i] = *(const float4*)(p + i * 256);
        v[i].x = (v[i].x == 0.f) ? -INFINITY : v[i].x;
        v[i].y = (v[i].y == 0.f) ? -INFINITY : v[i].y;
        v[i].z = (v[i].z == 0.f) ? -INFINITY : v[i].z;
        v[i].w = (v[i].w == 0.f) ? -INFINITY : v[i].w;
        mx = fmaxf(mx, fmaxf(fmaxf(v[i].x, v[i].y), fmaxf(v[i].z, v[i].w)));
    }
#pragma unroll
    for (int o = 32; o > 0; o >>= 1) mx = fmaxf(mx, __shfl_xor(mx, o, 64));

    float sum = 0.f;
#pragma unroll
    for (int i = 0; i < 4; ++i) {
        v[i].x = __expf(v[i].x - mx); v[i].y = __expf(v[i].y - mx);
        v[i].z = __expf(v[i].z - mx); v[i].w = __expf(v[i].w - mx);
        sum += v[i].x + v[i].y + v[i].z + v[i].w;
    }
#pragma unroll
    for (int o = 32; o > 0; o >>= 1) sum += __shfl_xor(sum, o, 64);

    const float inv = 1.f / sum;
#pragma unroll
    for (int i = 0; i < 4; ++i) {
        ushort4 u;
        u.x = f2h(v[i].x * inv); u.y = f2h(v[i].y * inv);
        u.z = f2h(v[i].z * inv); u.w = f2h(v[i].w * inv);
        *(ushort4*)(pb + i * 256) = u;
    }
}

// ================================================================ fallback
// (verified round-1 fp32 path, used only if ws_size < 264 MiB)
#define BM 128
#define BN 128
#define BKT 16

template<bool BT, bool DO_TANH, bool CAT_A>
__global__ __launch_bounds__(256)
void sgemm(const float* __restrict__ A, const float* __restrict__ A2,
           const float* __restrict__ Bmat, const float* __restrict__ bias,
           float* __restrict__ C,
           int M, int N, int K, int Ksplit,
           int lda, int ldb, int ldc,
           long sA, long sB, long sC)
{
    __shared__ float Asb[BKT][BM];
    __shared__ float Bsb[BKT][BN];

    const int bz = blockIdx.z;
    const float* Ab = A + (long)bz * sA;
    const float* Bb = Bmat + (long)bz * sB;
    float* Cb = C + (long)bz * sC;

    const int tid = threadIdx.x;
    const int m0 = blockIdx.y * BM;
    const int n0 = blockIdx.x * BN;
    const int tx = tid & 15;
    const int ty = tid >> 4;

    float acc[8][8];
#pragma unroll
    for (int i = 0; i < 8; ++i)
#pragma unroll
        for (int j = 0; j < 8; ++j) acc[i][j] = 0.f;

    for (int kk = 0; kk < K; kk += BKT) {
        const float* Asrc = Ab;
        int acol = kk;
        if constexpr (CAT_A) {
            if (kk >= Ksplit) { Asrc = A2; acol = kk - Ksplit; }
        }
#pragma unroll
        for (int i = 0; i < 2; ++i) {
            int f = i * 256 + tid;
            int row = f >> 2;
            int k4 = (f & 3) << 2;
            float4 v = *(const float4*)(Asrc + (long)(m0 + row) * lda + acol + k4);
            Asb[k4 + 0][row] = v.x; Asb[k4 + 1][row] = v.y;
            Asb[k4 + 2][row] = v.z; Asb[k4 + 3][row] = v.w;
        }
        if constexpr (BT) {
#pragma unroll
            for (int i = 0; i < 2; ++i) {
                int f = i * 256 + tid;
                int row = f >> 2;
                int k4 = (f & 3) << 2;
                float4 v = *(const float4*)(Bb + (long)(n0 + row) * ldb + kk + k4);
                Bsb[k4 + 0][row] = v.x; Bsb[k4 + 1][row] = v.y;
                Bsb[k4 + 2][row] = v.z; Bsb[k4 + 3][row] = v.w;
            }
        } else {
#pragma unroll
            for (int i = 0; i < 2; ++i) {
                int f = i * 256 + tid;
                int kr = f >> 5;
                int n4 = (f & 31) << 2;
                float4 v = *(const float4*)(Bb + (long)(kk + kr) * ldb + n0 + n4);
                *(float4*)&Bsb[kr][n4] = v;
            }
        }
        __syncthreads();
#pragma unroll
        for (int k = 0; k < BKT; ++k) {
            float a[8], bv[8];
            *(float4*)&a[0]  = *(const float4*)&Asb[k][ty * 4];
            *(float4*)&a[4]  = *(const float4*)&Asb[k][ty * 4 + 64];
            *(float4*)&bv[0] = *(const float4*)&Bsb[k][tx * 4];
            *(float4*)&bv[4] = *(const float4*)&Bsb[k][tx * 4 + 64];
#pragma unroll
            for (int i = 0; i < 8; ++i)
#pragma unroll
                for (int j = 0; j < 8; ++j)
                    acc[i][j] = fmaf(a[i], bv[j], acc[i][j]);
        }
        __syncthreads();
    }
#pragma unroll
    for (int i = 0; i < 8; ++i) {
        int rrow = m0 + ty * 4 + (i & 3) + ((i >> 2) << 6);
        float* crow = Cb + (long)rrow * ldc;
#pragma unroll
        for (int jj = 0; jj < 2; ++jj) {
            int c0 = n0 + tx * 4 + jj * 64;
            float4 v;
            v.x = acc[i][jj * 4 + 0]; v.y = acc[i][jj * 4 + 1];
            v.z = acc[i][jj * 4 + 2]; v.w = acc[i][jj * 4 + 3];
            if constexpr (DO_TANH) {
                v.x = tanhf(v.x + bias[c0 + 0]); v.y = tanhf(v.y + bias[c0 + 1]);
                v.z = tanhf(v.z + bias[c0 + 2]); v.w = tanhf(v.w + bias[c0 + 3]);
            }
            *(float4*)(crow + c0) = v;
        }
    }
}

__global__ __launch_bounds__(256)
void softmax_rows(float* __restrict__ P)
{
    const int row = blockIdx.x * 4 + (threadIdx.x >> 6);
    const int lane = threadIdx.x & 63;
    float* p = P + (long)row * 1024 + lane * 4;
    float4 v[4];
    float mx = -INFINITY;
#pragma unroll
    for (int i = 0; i < 4; ++i) {
        v[i] = *(const float4*)(p + i * 256);
        v[i].x = (v[i].x == 0.f) ? -INFINITY : v[i].x;
        v[i].y = (v[i].y == 0.f) ? -INFINITY : v[i].y;
        v[i].z = (v[i].z == 0.f) ? -INFINITY : v[i].z;
        v[i].w = (v[i].w == 0.f) ? -INFINITY : v[i].w;
        mx = fmaxf(mx, fmaxf(fmaxf(v[i].x, v[i].y), fmaxf(v[i].z, v[i].w)));
    }
#pragma unroll
    for (int o = 32; o > 0; o >>= 1) mx = fmaxf(mx, __shfl_xor(mx, o, 64));
    float sum = 0.f;
#pragma unroll
    for (int i = 0; i < 4; ++i) {
        v[i].x = __expf(v[i].x - mx); v[i].y = __expf(v[i].y - mx);
        v[i].z = __expf(v[i].z - mx); v[i].w = __expf(v[i].w - mx);
        sum += v[i].x + v[i].y + v[i].z + v[i].w;
    }
#pragma unroll
    for (int o = 32; o > 0; o >>= 1) sum += __shfl_xor(sum, o, 64);
    const float inv = 1.f / sum;
#pragma unroll
    for (int i = 0; i < 4; ++i) {
        v[i].x *= inv; v[i].y *= inv; v[i].z *= inv; v[i].w *= inv;
        *(float4*)(p + i * 256) = v[i];
    }
}

// ================================================================ launch
extern "C" void kernel_launch(void* const* d_in, const int* in_sizes, int n_in,
                              void* d_out, int out_size, void* d_ws, size_t ws_size,
                              hipStream_t stream)
{
    (void)in_sizes; (void)n_in; (void)out_size;
    const int Bv = 32, T = 512, S = 1024, H = 1024;

    const float* q     = (const float*)d_in[0];
    const float* enc   = (const float*)d_in[1];
    const float* W_in  = (const float*)d_in[3];
    const float* W_out = (const float*)d_in[4];
    const float* b_out = (const float*)d_in[5];
    float* out = (float*)d_out;

    const size_t need = 264ull << 20;
    if (ws_size >= need) {
        const bool big = ws_size >= (360ull << 20);

        char* w = (char*)d_ws;
        unsigned short* q_hi  = (unsigned short*)(w);                  // K1
        unsigned short* q_lo  = (unsigned short*)(w + (32ull << 20));  // K1; then Pb fp16
        unsigned short* z_hi  = (unsigned short*)(w + (64ull << 20));  // K1->K2; then C_f16
        unsigned short* z_lo  = (unsigned short*)(w + (96ull << 20));  // K1->K2; then q_f16 (small ws)
        unsigned short* e_hi  = (unsigned short*)(w + (128ull << 20)); // K2
        unsigned short* e_lo  = (unsigned short*)(w + (192ull << 20)); // K2; then eT fp16 (small ws)
        unsigned short* Wi_hi = (unsigned short*)(w + (256ull << 20));
        unsigned short* Wi_lo = (unsigned short*)(w + (258ull << 20));
        unsigned short* Wo16  = (unsigned short*)(w + (260ull << 20));
        // big-ws extras (past 264 MiB):
        unsigned short* q16b  = (unsigned short*)(w + (264ull << 20)); // 32 MiB
        unsigned short* eTb   = (unsigned short*)(w + (296ull << 20)); // 64 MiB

        unsigned short* Pb  = q_lo;                 // fp16, after softmax
        unsigned short* q16 = big ? q16b : z_lo;    // fp16
        unsigned short* eT  = big ? eTb  : e_lo;    // fp16
        unsigned short* C16 = z_hi;                 // fp16, after K2

        // ---- prep passes (read q and enc once when ws allows)
        if (big) split_q_k<true ><<<16384, 256, 0, stream>>>(q, q_hi, q_lo, q16b, 4194304);
        else     split_q_k<false><<<16384, 256, 0, stream>>>(q, q_hi, q_lo, nullptr, 4194304);
        prep_w_k<<<3072, 256, 0, stream>>>(W_in, Wi_hi, Wi_lo, W_out, Wo16);
        if (big) split_enc_t<<<dim3(16, 16, 32), 256, 0, stream>>>(enc, e_hi, e_lo, eTb);
        else     split_f32_bf16<<<32768, 256, 0, stream>>>(enc, e_hi, e_lo, 8388608);

        // K1: z = q·W_in^T  (chunk-fused bf16x3), out z_hi/z_lo   [XCD swizzle]
        gemm_x3<1, true><<<dim3(8, 128, 1), 256, 0, stream>>>(
            q_hi, q_lo, Wi_hi, Wi_lo,
            nullptr, z_hi, z_lo,
            1024, 1024, 1024, 1024, 0, 0, 0);

        // K2: P_b = z_b·enc_b^T (chunk-fused bf16x3), fp32 -> d_out
        gemm_x3<2, false><<<dim3(8, 4, 32), 256, 0, stream>>>(
            z_hi, z_lo, e_hi, e_lo,
            (float*)d_out, nullptr, nullptr,
            1024, 1024, (long)Bv * H, 1024,
            (long)T * H, (long)H, (long)T * S);

        // K3: masked softmax, fp32 -> fp16 Pb
        softmax_p_f16<<<(Bv * T) / 4, 256, 0, stream>>>((const float*)d_out, Pb);

        // small-ws: materialize q16/eT now (slots freed by K2)
        if (!big) {
            conv_f32_f16<<<16384, 256, 0, stream>>>(q, q16, 4194304);
            transpose_enc_f16<<<dim3(16, 16, 32), 256, 0, stream>>>(enc, eT);
        }

        // K4: C_b = Pb_b · eT_b^T  (fp16), out C_f16
        gemm_f16<1, 0, false><<<dim3(8, 4, 32), 256, 0, stream>>>(
            Pb, nullptr, eT, nullptr,
            nullptr, C16, nullptr,
            1024, 1024, 1024, 1024,
            (long)T * S, (long)H * S, (long)T * H);

        // K5: out = tanh([C,q]·W_out^T + b)  (fp16, 2 chunks)   [XCD swizzle]
        gemm_f16<2, 3, true><<<dim3(8, 128, 1), 256, 0, stream>>>(
            C16, q16, Wo16, Wo16 + 1024,
            (float*)d_out, nullptr, b_out,
            1024, 1024, 2048, 1024, 0, 0, 0);
    } else {
        // -------- fallback: round-1 fp32 path --------
        float* Z = (float*)d_ws;
        float* P = Z + (size_t)Bv * T * H;
        dim3 blk(256);
        sgemm<true, false, false><<<dim3(H / BN, (Bv * T) / BM, 1), blk, 0, stream>>>(
            q, nullptr, W_in, nullptr, Z,
            Bv * T, H, H, 0, H, H, H, 0, 0, 0);
        sgemm<true, false, false><<<dim3(S / BN, T / BM, Bv), blk, 0, stream>>>(
            Z, nullptr, enc, nullptr, P,
            T, S, H, 0, H, Bv * H, S, (long)T * H, H, (long)T * S);
        softmax_rows<<<(Bv * T) / 4, blk, 0, stream>>>(P);
        sgemm<false, false, false><<<dim3(H / BN, T / BM, Bv), blk, 0, stream>>>(
            P, nullptr, enc, nullptr, Z,
            T, H, S, 0, S, Bv * H, H, (long)T * S, H, (long)T * H);
        sgemm<true, true, true><<<dim3(H / BN, (Bv * T) / BM, 1), blk, 0, stream>>>(
            Z, q, W_out, b_out, out,
            Bv * T, H, 2 * H, H, H, 2 * H, H, 0, 0, 0);
    }
}